// Round 1
// baseline (401.432 us; speedup 1.0000x reference)
//
#include <hip/hip_runtime.h>
#include <hip/hip_bf16.h>

// Problem constants
constexpr int B  = 128;
constexpr int C  = 235;
constexpr int N  = 21;
constexpr int HW = 4096;   // 64*64
constexpr int HO = 128;    // heads*fo
constexpr int E  = 41;     // 20 skeleton edges + 21 self loops

// ---------------- K1: q[b,n,c] = sum_p t[b,n,p] * f[b,c,p] ----------------
// grid = (4 c-tiles, 128 b), block = 256 (4 waves). Wave w handles n-group,
// lane = c within tile. KB=128 K-chunk staged in LDS, +4 float pad.
constexpr int KB = 128;
constexpr int CT = 64;

__global__ __launch_bounds__(256) void k1_qgemm(
    const float* __restrict__ f,   // [B][C][HW]
    const float* __restrict__ t,   // [B][N][HW]
    float* __restrict__ q)         // [B][N][C]
{
    __shared__ float fl[CT][KB + 4];
    __shared__ float tl[N][KB + 4];

    const int b    = blockIdx.y;
    const int c0   = blockIdx.x * CT;
    const int tid  = threadIdx.x;
    const int lane = tid & 63;
    const int wave = tid >> 6;
    const int nstart = (wave == 0) ? 0 : 6 + (wave - 1) * 5;
    const int ncnt   = (wave == 0) ? 6 : 5;

    const float* fb = f + (size_t)b * C * HW;
    const float* tb = t + (size_t)b * N * HW;

    float acc[6] = {0.f, 0.f, 0.f, 0.f, 0.f, 0.f};

    for (int k0 = 0; k0 < HW; k0 += KB) {
        __syncthreads();   // protect LDS from previous iteration's readers
        // stage f tile: CT rows x KB floats = 2048 float4
        for (int v = tid; v < CT * (KB / 4); v += 256) {
            const int r  = v >> 5;      // KB/4 == 32 float4 per row
            const int c4 = v & 31;
            const int c  = c0 + r;
            float4 val = make_float4(0.f, 0.f, 0.f, 0.f);
            if (c < C)
                val = *reinterpret_cast<const float4*>(fb + (size_t)c * HW + k0 + c4 * 4);
            *reinterpret_cast<float4*>(&fl[r][c4 * 4]) = val;
        }
        // stage t tile: 21 rows x KB floats = 672 float4
        for (int v = tid; v < N * (KB / 4); v += 256) {
            const int r  = v >> 5;
            const int c4 = v & 31;
            float4 val = *reinterpret_cast<const float4*>(tb + (size_t)r * HW + k0 + c4 * 4);
            *reinterpret_cast<float4*>(&tl[r][c4 * 4]) = val;
        }
        __syncthreads();
        // compute: per thread 1 c-column x ncnt n-rows
        #pragma unroll 4
        for (int k = 0; k < KB; k += 4) {
            const float4 fv = *reinterpret_cast<const float4*>(&fl[lane][k]);
            #pragma unroll
            for (int i = 0; i < 6; i++) {
                if (i < ncnt) {
                    const float4 tv = *reinterpret_cast<const float4*>(&tl[nstart + i][k]);
                    acc[i] += fv.x * tv.x;
                    acc[i] += fv.y * tv.y;
                    acc[i] += fv.z * tv.z;
                    acc[i] += fv.w * tv.w;
                }
            }
        }
    }

    const int c = c0 + lane;
    if (c < C) {
        for (int i = 0; i < ncnt; i++)
            q[((size_t)b * N + nstart + i) * C + c] = acc[i];
    }
}

// ---------------- K2: BN stats per joint over (B, C) ----------------
__global__ __launch_bounds__(256) void k2_bnstats(
    const float* __restrict__ q,       // [B][N][C]
    const float* __restrict__ gamma,   // [N]
    const float* __restrict__ beta,    // [N]
    float* __restrict__ stats)         // [N][2] -> scale, shift
{
    const int n = blockIdx.x;
    const int tid = threadIdx.x;
    float s = 0.f, s2 = 0.f;
    if (tid < C) {
        for (int b = 0; b < B; b++) {
            const float v = q[((size_t)b * N + n) * C + tid];
            s += v; s2 += v * v;
        }
    }
    // wave reduce (wave = 64)
    for (int off = 32; off; off >>= 1) {
        s  += __shfl_down(s,  off);
        s2 += __shfl_down(s2, off);
    }
    __shared__ float rs[4], rs2[4];
    const int wave = tid >> 6, lane = tid & 63;
    if (lane == 0) { rs[wave] = s; rs2[wave] = s2; }
    __syncthreads();
    if (tid == 0) {
        const float S  = rs[0] + rs[1] + rs[2] + rs[3];
        const float S2 = rs2[0] + rs2[1] + rs2[2] + rs2[3];
        const float cnt = (float)(B * C);
        const float mean = S / cnt;
        const float var  = S2 / cnt - mean * mean;
        const float scale = gamma[n] * rsqrtf(var + 1e-5f);
        stats[2 * n]     = scale;
        stats[2 * n + 1] = beta[n] - mean * scale;
    }
}

// ---------------- K3: BN-apply + LeakyReLU + GAT + Cheb ----------------
__global__ __launch_bounds__(256) void k3_tail(
    const float* __restrict__ q,        // [B][N][C]
    const float* __restrict__ stats,    // [N][2]
    const float* __restrict__ gatw,     // [C][HO]
    const float* __restrict__ attsrc,   // [4][32]
    const float* __restrict__ attdst,   // [4][32]
    const float* __restrict__ gatbias,  // [HO]
    const float* __restrict__ chebw,    // [2][HO][3]
    const float* __restrict__ chebbias, // [3]
    const float* __restrict__ adj,      // [N][N]
    const int* __restrict__ esrc,
    const int* __restrict__ edst,
    float* __restrict__ out)            // [B][N][3]
{
    __shared__ float ql[N][C + 1];
    __shared__ float Wl[48][HO];
    __shared__ float hl[N][HO];
    __shared__ float xl[N][HO];
    __shared__ float asrcl[N][4], adstl[N][4];
    __shared__ float el[E][4], alphal[E][4];
    __shared__ float mx[N][4], den[N][4];
    __shared__ float zl[N][3], t0l[N][3], dsl[N];
    __shared__ int esl[E], edl[E];

    const int b = blockIdx.x;
    const int tid = threadIdx.x;

    // load q[b], apply BN + LeakyReLU(0.1)
    for (int v = tid; v < N * C; v += 256) {
        const int n = v / C, c = v % C;
        float x = q[((size_t)b * N + n) * C + c];
        x = x * stats[2 * n] + stats[2 * n + 1];
        ql[n][c] = (x >= 0.f) ? x : 0.1f * x;
    }
    if (tid < E) { esl[tid] = esrc[tid]; edl[tid] = edst[tid]; }
    for (int v = tid; v < N * HO; v += 256) hl[v >> 7][v & 127] = 0.f;
    __syncthreads();

    // h = ql @ gat_w, W chunked through LDS
    for (int k0 = 0; k0 < C; k0 += 48) {
        const int kc = (C - k0) < 48 ? (C - k0) : 48;
        for (int v = tid; v < kc * HO; v += 256) {
            const int kk = v >> 7, o = v & 127;
            Wl[kk][o] = gatw[(size_t)(k0 + kk) * HO + o];
        }
        __syncthreads();
        for (int idx = tid; idx < N * HO; idx += 256) {
            const int n = idx >> 7, o = idx & 127;
            float s = hl[n][o];
            for (int kk = 0; kk < kc; kk++)
                s += ql[n][k0 + kk] * Wl[kk][o];
            hl[n][o] = s;
        }
        __syncthreads();
    }

    // attention scores
    if (tid < N * 4) {
        const int n = tid >> 2, h = tid & 3;
        float ss = 0.f, sd = 0.f;
        for (int fo = 0; fo < 32; fo++) {
            const float hv = hl[n][h * 32 + fo];
            ss += hv * attsrc[h * 32 + fo];
            sd += hv * attdst[h * 32 + fo];
        }
        asrcl[n][h] = ss; adstl[n][h] = sd;
    }
    __syncthreads();
    if (tid < E * 4) {
        const int e = tid >> 2, h = tid & 3;
        const float v = asrcl[esl[e]][h] + adstl[edl[e]][h];
        el[e][h] = (v >= 0.f) ? v : 0.2f * v;   // negative_slope 0.2
    }
    __syncthreads();
    if (tid < N * 4) {
        const int n = tid >> 2, h = tid & 3;
        float m = -1e30f;
        for (int e = 0; e < E; e++)
            if (edl[e] == n) m = fmaxf(m, el[e][h]);
        mx[n][h] = m;
    }
    __syncthreads();
    if (tid < E * 4) {
        const int e = tid >> 2, h = tid & 3;
        el[e][h] = __expf(el[e][h] - mx[edl[e]][h]);
    }
    __syncthreads();
    if (tid < N * 4) {
        const int n = tid >> 2, h = tid & 3;
        float s = 0.f;
        for (int e = 0; e < E; e++)
            if (edl[e] == n) s += el[e][h];
        den[n][h] = s;
    }
    __syncthreads();
    if (tid < E * 4) {
        const int e = tid >> 2, h = tid & 3;
        alphal[e][h] = el[e][h] / den[edl[e]][h];
    }
    __syncthreads();

    // aggregate messages: x[n][o] = sum_{e: dst==n} alpha[e][h] * h[src[e]][o]
    for (int idx = tid; idx < N * HO; idx += 256) {
        const int n = idx >> 7, o = idx & 127, h = o >> 5;
        float s = 0.f;
        for (int e = 0; e < E; e++)
            if (edl[e] == n) s += alphal[e][h] * hl[esl[e]][o];
        xl[n][o] = s + gatbias[o];
    }
    // degree scaling for Laplacian
    if (tid < N) {
        float s = 0.f;
        for (int j = 0; j < N; j++) s += adj[tid * N + j];
        dsl[tid] = rsqrtf(s);
    }
    __syncthreads();

    // Cheb: y = x@W0 + (I - D^-1/2 A D^-1/2)(x@W1) + bias
    if (tid < N * 3) {
        const int n = tid / 3, o = tid % 3;
        float s0 = 0.f, sz = 0.f;
        for (int c2 = 0; c2 < HO; c2++) {
            const float xv = xl[n][c2];
            s0 += xv * chebw[(size_t)c2 * 3 + o];
            sz += xv * chebw[(size_t)(HO + c2) * 3 + o];
        }
        t0l[n][o] = s0; zl[n][o] = sz;
    }
    __syncthreads();
    if (tid < N * 3) {
        const int m = tid / 3, o = tid % 3;
        float s = t0l[m][o] + zl[m][o];
        for (int n2 = 0; n2 < N; n2++)
            s -= dsl[m] * adj[m * N + n2] * dsl[n2] * zl[n2][o];
        out[(size_t)b * N * 3 + tid] = s + chebbias[o];
    }
}

extern "C" void kernel_launch(void* const* d_in, const int* in_sizes, int n_in,
                              void* d_out, int out_size, void* d_ws, size_t ws_size,
                              hipStream_t stream) {
    const float* feature  = (const float*)d_in[0];
    const float* target   = (const float*)d_in[1];
    const float* gamma    = (const float*)d_in[2];
    const float* beta     = (const float*)d_in[3];
    const float* gatw     = (const float*)d_in[4];
    const float* attsrc   = (const float*)d_in[5];
    const float* attdst   = (const float*)d_in[6];
    const float* gatbias  = (const float*)d_in[7];
    const float* chebw    = (const float*)d_in[8];
    const float* chebbias = (const float*)d_in[9];
    const float* adj      = (const float*)d_in[10];
    const int*   esrc     = (const int*)d_in[11];
    const int*   edst     = (const int*)d_in[12];

    float* q     = (float*)d_ws;                    // [B][N][C]
    float* stats = q + (size_t)B * N * C;           // [N][2]
    float* out   = (float*)d_out;

    hipLaunchKernelGGL(k1_qgemm, dim3(4, B), dim3(256), 0, stream, feature, target, q);
    hipLaunchKernelGGL(k2_bnstats, dim3(N), dim3(256), 0, stream, q, gamma, beta, stats);
    hipLaunchKernelGGL(k3_tail, dim3(B), dim3(256), 0, stream,
                       q, stats, gatw, attsrc, attdst, gatbias, chebw, chebbias,
                       adj, esrc, edst, out);
}

// Round 2
// 306.563 us; speedup vs baseline: 1.3095x; 1.3095x over previous
//
#include <hip/hip_runtime.h>
#include <hip/hip_bf16.h>

// Problem constants
constexpr int B  = 128;
constexpr int C  = 235;
constexpr int N  = 21;
constexpr int HW = 4096;   // 64*64
constexpr int HO = 128;    // heads*fo
constexpr int E  = 41;     // 20 skeleton edges + 21 self loops

// ---------------- K1: q[b,n,c] = sum_p t[b,n,p] * f[b,c,p] ----------------
// v2: t read via wave-uniform global loads (no LDS), f LDS-staged.
// 2 c per thread (CT2=128), K split 4 ways -> 1024 blocks, 4/CU.
constexpr int KSPLIT = 4;
constexpr int KRANGE = HW / KSPLIT;   // 1024
constexpr int KB  = 64;
constexpr int CT2 = 128;

__global__ __launch_bounds__(256, 4) void k1_qgemm(
    const float* __restrict__ f,   // [B][C][HW]
    const float* __restrict__ t,   // [B][N][HW]
    float* __restrict__ qp)        // [KSPLIT][B][N][C] partials
{
    __shared__ float fl[CT2][KB + 4];

    const int b   = blockIdx.z;
    const int ks  = blockIdx.y;
    const int c0  = blockIdx.x * CT2;
    const int tid = threadIdx.x;
    const int lane = tid & 63;
    const int wave = __builtin_amdgcn_readfirstlane(tid >> 6);
    const int nstart = (wave == 0) ? 0 : 6 + (wave - 1) * 5;
    const int ncnt   = (wave == 0) ? 6 : 5;

    const float* fb = f + (size_t)b * C * HW;
    const float* tb = t + (size_t)b * N * HW;

    float acc[2][6] = {};
    const int kbase = ks * KRANGE;

    for (int k0 = kbase; k0 < kbase + KRANGE; k0 += KB) {
        __syncthreads();
        // stage f tile: 128 rows x 64 floats = 2048 float4, 8 per thread
        #pragma unroll
        for (int i = 0; i < 8; i++) {
            const int v  = tid + i * 256;
            const int r  = v >> 4;          // 16 float4 per row
            const int c4 = v & 15;
            const int c  = c0 + r;
            float4 val = make_float4(0.f, 0.f, 0.f, 0.f);
            if (c < C)
                val = *reinterpret_cast<const float4*>(fb + (size_t)c * HW + k0 + c4 * 4);
            *reinterpret_cast<float4*>(&fl[r][c4 * 4]) = val;
        }
        __syncthreads();

        #pragma unroll 2
        for (int k = 0; k < KB; k += 4) {
            // wave-uniform t loads (scalarizable: n, k, b all uniform)
            float4 tv[6];
            #pragma unroll
            for (int i = 0; i < 6; i++)
                if (i < ncnt)
                    tv[i] = *reinterpret_cast<const float4*>(
                        tb + (size_t)(nstart + i) * HW + k0 + k);
            const float4 f0 = *reinterpret_cast<const float4*>(&fl[lane][k]);
            const float4 f1 = *reinterpret_cast<const float4*>(&fl[lane + 64][k]);
            #pragma unroll
            for (int i = 0; i < 6; i++) {
                if (i < ncnt) {
                    acc[0][i] += f0.x * tv[i].x + f0.y * tv[i].y
                               + f0.z * tv[i].z + f0.w * tv[i].w;
                    acc[1][i] += f1.x * tv[i].x + f1.y * tv[i].y
                               + f1.z * tv[i].z + f1.w * tv[i].w;
                }
            }
        }
    }

    float* qpk = qp + (size_t)ks * B * N * C;
    for (int i = 0; i < ncnt; i++) {
        const size_t rowoff = ((size_t)b * N + nstart + i) * C;
        int c = c0 + lane;
        if (c < C) qpk[rowoff + c] = acc[0][i];
        c = c0 + 64 + lane;
        if (c < C) qpk[rowoff + c] = acc[1][i];
    }
}

// ---------------- K1b: reduce 4 K-split partials ----------------
__global__ __launch_bounds__(256) void k1b_reduce(
    const float* __restrict__ qp, float* __restrict__ q)
{
    const int i = blockIdx.x * 256 + threadIdx.x;
    constexpr int S = B * N * C;
    if (i < S)
        q[i] = qp[i] + qp[S + i] + qp[2 * S + i] + qp[3 * S + i];
}

// ---------------- K2: BN stats per joint over (B, C) ----------------
__global__ __launch_bounds__(256) void k2_bnstats(
    const float* __restrict__ q,       // [B][N][C]
    const float* __restrict__ gamma,   // [N]
    const float* __restrict__ beta,    // [N]
    float* __restrict__ stats)         // [N][2] -> scale, shift
{
    const int n = blockIdx.x;
    const int tid = threadIdx.x;
    float s = 0.f, s2 = 0.f;
    if (tid < C) {
        for (int b = 0; b < B; b++) {
            const float v = q[((size_t)b * N + n) * C + tid];
            s += v; s2 += v * v;
        }
    }
    for (int off = 32; off; off >>= 1) {
        s  += __shfl_down(s,  off);
        s2 += __shfl_down(s2, off);
    }
    __shared__ float rs[4], rs2[4];
    const int wave = tid >> 6, lane = tid & 63;
    if (lane == 0) { rs[wave] = s; rs2[wave] = s2; }
    __syncthreads();
    if (tid == 0) {
        const float S  = rs[0] + rs[1] + rs[2] + rs[3];
        const float S2 = rs2[0] + rs2[1] + rs2[2] + rs2[3];
        const float cnt = (float)(B * C);
        const float mean = S / cnt;
        const float var  = S2 / cnt - mean * mean;
        const float scale = gamma[n] * rsqrtf(var + 1e-5f);
        stats[2 * n]     = scale;
        stats[2 * n + 1] = beta[n] - mean * scale;
    }
}

// ---------------- K3: BN-apply + LeakyReLU + GAT + Cheb ----------------
__global__ __launch_bounds__(256) void k3_tail(
    const float* __restrict__ q,        // [B][N][C]
    const float* __restrict__ stats,    // [N][2]
    const float* __restrict__ gatw,     // [C][HO]
    const float* __restrict__ attsrc,   // [4][32]
    const float* __restrict__ attdst,   // [4][32]
    const float* __restrict__ gatbias,  // [HO]
    const float* __restrict__ chebw,    // [2][HO][3]
    const float* __restrict__ chebbias, // [3]
    const float* __restrict__ adj,      // [N][N]
    const int* __restrict__ esrc,
    const int* __restrict__ edst,
    float* __restrict__ out)            // [B][N][3]
{
    __shared__ float ql[N][C + 1];
    __shared__ float Wl[48][HO];
    __shared__ float hl[N][HO];
    __shared__ float xl[N][HO];
    __shared__ float asrcl[N][4], adstl[N][4];
    __shared__ float el[E][4], alphal[E][4];
    __shared__ float mx[N][4], den[N][4];
    __shared__ float zl[N][3], t0l[N][3], dsl[N];
    __shared__ int esl[E], edl[E];

    const int b = blockIdx.x;
    const int tid = threadIdx.x;

    for (int v = tid; v < N * C; v += 256) {
        const int n = v / C, c = v % C;
        float x = q[((size_t)b * N + n) * C + c];
        x = x * stats[2 * n] + stats[2 * n + 1];
        ql[n][c] = (x >= 0.f) ? x : 0.1f * x;
    }
    if (tid < E) { esl[tid] = esrc[tid]; edl[tid] = edst[tid]; }
    for (int v = tid; v < N * HO; v += 256) hl[v >> 7][v & 127] = 0.f;
    __syncthreads();

    for (int k0 = 0; k0 < C; k0 += 48) {
        const int kc = (C - k0) < 48 ? (C - k0) : 48;
        for (int v = tid; v < kc * HO; v += 256) {
            const int kk = v >> 7, o = v & 127;
            Wl[kk][o] = gatw[(size_t)(k0 + kk) * HO + o];
        }
        __syncthreads();
        for (int idx = tid; idx < N * HO; idx += 256) {
            const int n = idx >> 7, o = idx & 127;
            float s = hl[n][o];
            for (int kk = 0; kk < kc; kk++)
                s += ql[n][k0 + kk] * Wl[kk][o];
            hl[n][o] = s;
        }
        __syncthreads();
    }

    if (tid < N * 4) {
        const int n = tid >> 2, h = tid & 3;
        float ss = 0.f, sd = 0.f;
        for (int fo = 0; fo < 32; fo++) {
            const float hv = hl[n][h * 32 + fo];
            ss += hv * attsrc[h * 32 + fo];
            sd += hv * attdst[h * 32 + fo];
        }
        asrcl[n][h] = ss; adstl[n][h] = sd;
    }
    __syncthreads();
    if (tid < E * 4) {
        const int e = tid >> 2, h = tid & 3;
        const float v = asrcl[esl[e]][h] + adstl[edl[e]][h];
        el[e][h] = (v >= 0.f) ? v : 0.2f * v;
    }
    __syncthreads();
    if (tid < N * 4) {
        const int n = tid >> 2, h = tid & 3;
        float m = -1e30f;
        for (int e = 0; e < E; e++)
            if (edl[e] == n) m = fmaxf(m, el[e][h]);
        mx[n][h] = m;
    }
    __syncthreads();
    if (tid < E * 4) {
        const int e = tid >> 2, h = tid & 3;
        el[e][h] = __expf(el[e][h] - mx[edl[e]][h]);
    }
    __syncthreads();
    if (tid < N * 4) {
        const int n = tid >> 2, h = tid & 3;
        float s = 0.f;
        for (int e = 0; e < E; e++)
            if (edl[e] == n) s += el[e][h];
        den[n][h] = s;
    }
    __syncthreads();
    if (tid < E * 4) {
        const int e = tid >> 2, h = tid & 3;
        alphal[e][h] = el[e][h] / den[edl[e]][h];
    }
    __syncthreads();

    for (int idx = tid; idx < N * HO; idx += 256) {
        const int n = idx >> 7, o = idx & 127, h = o >> 5;
        float s = 0.f;
        for (int e = 0; e < E; e++)
            if (edl[e] == n) s += alphal[e][h] * hl[esl[e]][o];
        xl[n][o] = s + gatbias[o];
    }
    if (tid < N) {
        float s = 0.f;
        for (int j = 0; j < N; j++) s += adj[tid * N + j];
        dsl[tid] = rsqrtf(s);
    }
    __syncthreads();

    if (tid < N * 3) {
        const int n = tid / 3, o = tid % 3;
        float s0 = 0.f, sz = 0.f;
        for (int c2 = 0; c2 < HO; c2++) {
            const float xv = xl[n][c2];
            s0 += xv * chebw[(size_t)c2 * 3 + o];
            sz += xv * chebw[(size_t)(HO + c2) * 3 + o];
        }
        t0l[n][o] = s0; zl[n][o] = sz;
    }
    __syncthreads();
    if (tid < N * 3) {
        const int m = tid / 3, o = tid % 3;
        float s = t0l[m][o] + zl[m][o];
        for (int n2 = 0; n2 < N; n2++)
            s -= dsl[m] * adj[m * N + n2] * dsl[n2] * zl[n2][o];
        out[(size_t)b * N * 3 + tid] = s + chebbias[o];
    }
}

extern "C" void kernel_launch(void* const* d_in, const int* in_sizes, int n_in,
                              void* d_out, int out_size, void* d_ws, size_t ws_size,
                              hipStream_t stream) {
    const float* feature  = (const float*)d_in[0];
    const float* target   = (const float*)d_in[1];
    const float* gamma    = (const float*)d_in[2];
    const float* beta     = (const float*)d_in[3];
    const float* gatw     = (const float*)d_in[4];
    const float* attsrc   = (const float*)d_in[5];
    const float* attdst   = (const float*)d_in[6];
    const float* gatbias  = (const float*)d_in[7];
    const float* chebw    = (const float*)d_in[8];
    const float* chebbias = (const float*)d_in[9];
    const float* adj      = (const float*)d_in[10];
    const int*   esrc     = (const int*)d_in[11];
    const int*   edst     = (const int*)d_in[12];

    constexpr int QS = B * N * C;
    float* qp    = (float*)d_ws;                    // [KSPLIT][B][N][C]
    float* q     = qp + (size_t)KSPLIT * QS;        // [B][N][C]
    float* stats = q + QS;                          // [N][2]
    float* out   = (float*)d_out;

    hipLaunchKernelGGL(k1_qgemm, dim3(2, KSPLIT, B), dim3(256), 0, stream,
                       feature, target, qp);
    hipLaunchKernelGGL(k1b_reduce, dim3((QS + 255) / 256), dim3(256), 0, stream, qp, q);
    hipLaunchKernelGGL(k2_bnstats, dim3(N), dim3(256), 0, stream, q, gamma, beta, stats);
    hipLaunchKernelGGL(k3_tail, dim3(B), dim3(256), 0, stream,
                       q, stats, gatw, attsrc, attdst, gatbias, chebw, chebbias,
                       adj, esrc, edst, out);
}

// Round 3
// 274.118 us; speedup vs baseline: 1.4644x; 1.1184x over previous
//
#include <hip/hip_runtime.h>
#include <hip/hip_bf16.h>

// Problem constants
constexpr int B  = 128;
constexpr int C  = 235;
constexpr int N  = 21;
constexpr int HW = 4096;   // 64*64
constexpr int HO = 128;    // heads*fo
constexpr int E  = 41;     // 20 skeleton edges + 21 self loops

// ---------------- K1: q[b,n,c] = sum_p t[b,n,p] * f[b,c,p] ----------------
// v3: both operands LDS-staged. tv reads are wave-uniform LDS broadcasts
// (free); fv reads are 2-way-aliased b128 (free). KSPLIT=8 -> 2048 blocks,
// 4 blocks/CU (LDS 40.2KB/block), 16 waves/CU.
constexpr int KSPLIT = 8;
constexpr int KRANGE = HW / KSPLIT;   // 512
constexpr int KB  = 64;
constexpr int CT2 = 128;
constexpr int FS  = KB + 4;           // 68 floats: 16B-aligned rows, <=2-way banks

__global__ __launch_bounds__(256, 4) void k1_qgemm(
    const float* __restrict__ f,   // [B][C][HW]
    const float* __restrict__ t,   // [B][N][HW]
    float* __restrict__ qp)        // [KSPLIT][B][N][C] partials
{
    __shared__ float fl[CT2][FS];  // 34816 B
    __shared__ float tl[N][KB];    // 5376 B  (total 40192 <= 40960)

    const int b   = blockIdx.z;
    const int ks  = blockIdx.y;
    const int c0  = blockIdx.x * CT2;
    const int tid = threadIdx.x;
    const int lane = tid & 63;
    const int wave = __builtin_amdgcn_readfirstlane(tid >> 6);
    const int nstart = (wave == 0) ? 0 : 6 + (wave - 1) * 5;
    const int ncnt   = (wave == 0) ? 6 : 5;

    const float* fb = f + (size_t)b * C * HW;
    const float* tb = t + (size_t)b * N * HW;

    float acc[2][6] = {};
    const int kbase = ks * KRANGE;

    for (int k0 = kbase; k0 < kbase + KRANGE; k0 += KB) {
        __syncthreads();
        // stage f tile: 128 rows x 64 floats = 2048 float4, 8 per thread
        #pragma unroll
        for (int i = 0; i < 8; i++) {
            const int v  = tid + i * 256;
            const int r  = v >> 4;          // 16 float4 per row
            const int c4 = v & 15;
            const int c  = c0 + r;
            float4 val = make_float4(0.f, 0.f, 0.f, 0.f);
            if (c < C)
                val = *reinterpret_cast<const float4*>(fb + (size_t)c * HW + k0 + c4 * 4);
            *reinterpret_cast<float4*>(&fl[r][c4 * 4]) = val;
        }
        // stage t tile: 21 rows x 64 floats = 336 float4
        for (int v = tid; v < N * (KB / 4); v += 256) {
            const int r  = v >> 4;
            const int c4 = v & 15;
            *reinterpret_cast<float4*>(&tl[r][c4 * 4]) =
                *reinterpret_cast<const float4*>(tb + (size_t)r * HW + k0 + c4 * 4);
        }
        __syncthreads();

        #pragma unroll 2
        for (int k = 0; k < KB; k += 4) {
            float4 tv[6];
            #pragma unroll
            for (int i = 0; i < 6; i++)
                if (i < ncnt)
                    tv[i] = *reinterpret_cast<const float4*>(&tl[nstart + i][k]);
            const float4 f0 = *reinterpret_cast<const float4*>(&fl[lane][k]);
            const float4 f1 = *reinterpret_cast<const float4*>(&fl[lane + 64][k]);
            #pragma unroll
            for (int i = 0; i < 6; i++) {
                if (i < ncnt) {
                    acc[0][i] += f0.x * tv[i].x + f0.y * tv[i].y
                               + f0.z * tv[i].z + f0.w * tv[i].w;
                    acc[1][i] += f1.x * tv[i].x + f1.y * tv[i].y
                               + f1.z * tv[i].z + f1.w * tv[i].w;
                }
            }
        }
    }

    float* qpk = qp + (size_t)ks * B * N * C;
    for (int i = 0; i < ncnt; i++) {
        const size_t rowoff = ((size_t)b * N + nstart + i) * C;
        int c = c0 + lane;
        if (c < C) qpk[rowoff + c] = acc[0][i];
        c = c0 + 64 + lane;
        if (c < C) qpk[rowoff + c] = acc[1][i];
    }
}

// ---------------- K1b: reduce KSPLIT partials ----------------
__global__ __launch_bounds__(256) void k1b_reduce(
    const float* __restrict__ qp, float* __restrict__ q)
{
    const int i = blockIdx.x * 256 + threadIdx.x;
    constexpr int S = B * N * C;
    if (i < S) {
        float s = 0.f;
        #pragma unroll
        for (int p = 0; p < KSPLIT; p++) s += qp[(size_t)p * S + i];
        q[i] = s;
    }
}

// ---------------- K2: BN stats per joint over (B, C) ----------------
__global__ __launch_bounds__(256) void k2_bnstats(
    const float* __restrict__ q,       // [B][N][C]
    const float* __restrict__ gamma,   // [N]
    const float* __restrict__ beta,    // [N]
    float* __restrict__ stats)         // [N][2] -> scale, shift
{
    const int n = blockIdx.x;
    const int tid = threadIdx.x;
    float s = 0.f, s2 = 0.f;
    if (tid < C) {
        for (int b = 0; b < B; b++) {
            const float v = q[((size_t)b * N + n) * C + tid];
            s += v; s2 += v * v;
        }
    }
    for (int off = 32; off; off >>= 1) {
        s  += __shfl_down(s,  off);
        s2 += __shfl_down(s2, off);
    }
    __shared__ float rs[4], rs2[4];
    const int wave = tid >> 6, lane = tid & 63;
    if (lane == 0) { rs[wave] = s; rs2[wave] = s2; }
    __syncthreads();
    if (tid == 0) {
        const float S  = rs[0] + rs[1] + rs[2] + rs[3];
        const float S2 = rs2[0] + rs2[1] + rs2[2] + rs2[3];
        const float cnt = (float)(B * C);
        const float mean = S / cnt;
        const float var  = S2 / cnt - mean * mean;
        const float scale = gamma[n] * rsqrtf(var + 1e-5f);
        stats[2 * n]     = scale;
        stats[2 * n + 1] = beta[n] - mean * scale;
    }
}

// ---------------- K3: BN-apply + LeakyReLU + GAT + Cheb ----------------
__global__ __launch_bounds__(256) void k3_tail(
    const float* __restrict__ q,        // [B][N][C]
    const float* __restrict__ stats,    // [N][2]
    const float* __restrict__ gatw,     // [C][HO]
    const float* __restrict__ attsrc,   // [4][32]
    const float* __restrict__ attdst,   // [4][32]
    const float* __restrict__ gatbias,  // [HO]
    const float* __restrict__ chebw,    // [2][HO][3]
    const float* __restrict__ chebbias, // [3]
    const float* __restrict__ adj,      // [N][N]
    const int* __restrict__ esrc,
    const int* __restrict__ edst,
    float* __restrict__ out)            // [B][N][3]
{
    __shared__ float ql[N][C + 1];
    __shared__ float Wl[48][HO];
    __shared__ float hl[N][HO];
    __shared__ float xl[N][HO];
    __shared__ float asrcl[N][4], adstl[N][4];
    __shared__ float el[E][4], alphal[E][4];
    __shared__ float mx[N][4], den[N][4];
    __shared__ float zl[N][3], t0l[N][3], dsl[N];
    __shared__ int esl[E], edl[E];

    const int b = blockIdx.x;
    const int tid = threadIdx.x;

    for (int v = tid; v < N * C; v += 256) {
        const int n = v / C, c = v % C;
        float x = q[((size_t)b * N + n) * C + c];
        x = x * stats[2 * n] + stats[2 * n + 1];
        ql[n][c] = (x >= 0.f) ? x : 0.1f * x;
    }
    if (tid < E) { esl[tid] = esrc[tid]; edl[tid] = edst[tid]; }
    for (int v = tid; v < N * HO; v += 256) hl[v >> 7][v & 127] = 0.f;
    __syncthreads();

    for (int k0 = 0; k0 < C; k0 += 48) {
        const int kc = (C - k0) < 48 ? (C - k0) : 48;
        for (int v = tid; v < kc * HO; v += 256) {
            const int kk = v >> 7, o = v & 127;
            Wl[kk][o] = gatw[(size_t)(k0 + kk) * HO + o];
        }
        __syncthreads();
        for (int idx = tid; idx < N * HO; idx += 256) {
            const int n = idx >> 7, o = idx & 127;
            float s = hl[n][o];
            for (int kk = 0; kk < kc; kk++)
                s += ql[n][k0 + kk] * Wl[kk][o];
            hl[n][o] = s;
        }
        __syncthreads();
    }

    if (tid < N * 4) {
        const int n = tid >> 2, h = tid & 3;
        float ss = 0.f, sd = 0.f;
        for (int fo = 0; fo < 32; fo++) {
            const float hv = hl[n][h * 32 + fo];
            ss += hv * attsrc[h * 32 + fo];
            sd += hv * attdst[h * 32 + fo];
        }
        asrcl[n][h] = ss; adstl[n][h] = sd;
    }
    __syncthreads();
    if (tid < E * 4) {
        const int e = tid >> 2, h = tid & 3;
        const float v = asrcl[esl[e]][h] + adstl[edl[e]][h];
        el[e][h] = (v >= 0.f) ? v : 0.2f * v;
    }
    __syncthreads();
    if (tid < N * 4) {
        const int n = tid >> 2, h = tid & 3;
        float m = -1e30f;
        for (int e = 0; e < E; e++)
            if (edl[e] == n) m = fmaxf(m, el[e][h]);
        mx[n][h] = m;
    }
    __syncthreads();
    if (tid < E * 4) {
        const int e = tid >> 2, h = tid & 3;
        el[e][h] = __expf(el[e][h] - mx[edl[e]][h]);
    }
    __syncthreads();
    if (tid < N * 4) {
        const int n = tid >> 2, h = tid & 3;
        float s = 0.f;
        for (int e = 0; e < E; e++)
            if (edl[e] == n) s += el[e][h];
        den[n][h] = s;
    }
    __syncthreads();
    if (tid < E * 4) {
        const int e = tid >> 2, h = tid & 3;
        alphal[e][h] = el[e][h] / den[edl[e]][h];
    }
    __syncthreads();

    for (int idx = tid; idx < N * HO; idx += 256) {
        const int n = idx >> 7, o = idx & 127, h = o >> 5;
        float s = 0.f;
        for (int e = 0; e < E; e++)
            if (edl[e] == n) s += alphal[e][h] * hl[esl[e]][o];
        xl[n][o] = s + gatbias[o];
    }
    if (tid < N) {
        float s = 0.f;
        for (int j = 0; j < N; j++) s += adj[tid * N + j];
        dsl[tid] = rsqrtf(s);
    }
    __syncthreads();

    if (tid < N * 3) {
        const int n = tid / 3, o = tid % 3;
        float s0 = 0.f, sz = 0.f;
        for (int c2 = 0; c2 < HO; c2++) {
            const float xv = xl[n][c2];
            s0 += xv * chebw[(size_t)c2 * 3 + o];
            sz += xv * chebw[(size_t)(HO + c2) * 3 + o];
        }
        t0l[n][o] = s0; zl[n][o] = sz;
    }
    __syncthreads();
    if (tid < N * 3) {
        const int m = tid / 3, o = tid % 3;
        float s = t0l[m][o] + zl[m][o];
        for (int n2 = 0; n2 < N; n2++)
            s -= dsl[m] * adj[m * N + n2] * dsl[n2] * zl[n2][o];
        out[(size_t)b * N * 3 + tid] = s + chebbias[o];
    }
}

extern "C" void kernel_launch(void* const* d_in, const int* in_sizes, int n_in,
                              void* d_out, int out_size, void* d_ws, size_t ws_size,
                              hipStream_t stream) {
    const float* feature  = (const float*)d_in[0];
    const float* target   = (const float*)d_in[1];
    const float* gamma    = (const float*)d_in[2];
    const float* beta     = (const float*)d_in[3];
    const float* gatw     = (const float*)d_in[4];
    const float* attsrc   = (const float*)d_in[5];
    const float* attdst   = (const float*)d_in[6];
    const float* gatbias  = (const float*)d_in[7];
    const float* chebw    = (const float*)d_in[8];
    const float* chebbias = (const float*)d_in[9];
    const float* adj      = (const float*)d_in[10];
    const int*   esrc     = (const int*)d_in[11];
    const int*   edst     = (const int*)d_in[12];

    constexpr int QS = B * N * C;
    float* qp    = (float*)d_ws;                    // [KSPLIT][B][N][C]
    float* q     = qp + (size_t)KSPLIT * QS;        // [B][N][C]
    float* stats = q + QS;                          // [N][2]
    float* out   = (float*)d_out;

    hipLaunchKernelGGL(k1_qgemm, dim3(2, KSPLIT, B), dim3(256), 0, stream,
                       feature, target, qp);
    hipLaunchKernelGGL(k1b_reduce, dim3((QS + 255) / 256), dim3(256), 0, stream, qp, q);
    hipLaunchKernelGGL(k2_bnstats, dim3(N), dim3(256), 0, stream, q, gamma, beta, stats);
    hipLaunchKernelGGL(k3_tail, dim3(B), dim3(256), 0, stream,
                       q, stats, gatw, attsrc, attdst, gatbias, chebw, chebbias,
                       adj, esrc, edst, out);
}

// Round 4
// 190.968 us; speedup vs baseline: 2.1021x; 1.4354x over previous
//
#include <hip/hip_runtime.h>
#include <hip/hip_bf16.h>

// Problem constants
constexpr int B  = 128;
constexpr int C  = 235;
constexpr int N  = 21;
constexpr int HW = 4096;   // 64*64
constexpr int HO = 128;    // heads*fo
constexpr int E  = 41;     // 20 skeleton edges + 21 self loops

typedef __attribute__((ext_vector_type(8)))  short  short8;   // 8 bf16 (4 VGPRs)
typedef __attribute__((ext_vector_type(16))) float  f32x16;   // 32x32 accum

__device__ inline unsigned short bf16r(float x) {
    return __bfloat16_as_ushort(__float2bfloat16(x));   // RNE
}

// ---------------- K1: q[b,n,c] = sum_p t[b,n,p] * f[b,c,p] ----------------
// v4: MFMA 32x32x16 bf16, NO LDS. M=21 fits one 32-row tile; each wave owns
// two 32-col N-tiles. Operands loaded straight from global in fragment
// layout: lane l -> row/col (l&31), k-slice (l>>5)*8 + j (32B contiguous;
// lanes l and l+32 cover one full 64B line). f32 -> bf16 in registers.
constexpr int KSPLIT = 8;
constexpr int KRANGE = HW / KSPLIT;   // 512

__global__ __launch_bounds__(256) void k1_qgemm(
    const float* __restrict__ f,   // [B][C][HW]
    const float* __restrict__ t,   // [B][N][HW]
    float* __restrict__ qp)        // [KSPLIT][B][N][C] partials
{
    const int b    = blockIdx.y;
    const int ks   = blockIdx.x;
    const int tid  = threadIdx.x;
    const int wave = tid >> 6;        // 0..3 -> N-tiles 2w, 2w+1
    const int lane = tid & 63;
    const int l31  = lane & 31;
    const int kh   = lane >> 5;       // k-half: 0 -> k 0..7, 1 -> k 8..15

    const float* fb = f + (size_t)b * C * HW;
    const float* tb = t + (size_t)b * N * HW;

    const int arow = (l31 < N) ? l31 : (N - 1);          // clamp pad rows
    const int c1   = wave * 64 + l31;                    // tile 2w
    const int c2   = wave * 64 + 32 + l31;               // tile 2w+1
    const int c1c  = (c1 < C) ? c1 : (C - 1);
    const int c2c  = (c2 < C) ? c2 : (C - 1);

    const float* pa = tb + (size_t)arow * HW + kh * 8;
    const float* p1 = fb + (size_t)c1c  * HW + kh * 8;
    const float* p2 = fb + (size_t)c2c  * HW + kh * 8;

    f32x16 acc0 = {};
    f32x16 acc1 = {};

    const int kend = ks * KRANGE + KRANGE;
    #pragma unroll 2
    for (int k = ks * KRANGE; k < kend; k += 16) {
        const float4 alo = *reinterpret_cast<const float4*>(pa + k);
        const float4 ahi = *reinterpret_cast<const float4*>(pa + k + 4);
        const float4 b1l = *reinterpret_cast<const float4*>(p1 + k);
        const float4 b1h = *reinterpret_cast<const float4*>(p1 + k + 4);
        const float4 b2l = *reinterpret_cast<const float4*>(p2 + k);
        const float4 b2h = *reinterpret_cast<const float4*>(p2 + k + 4);

        union { short8 v; unsigned short u[8]; } av, bv1, bv2;
        av.u[0]  = bf16r(alo.x); av.u[1]  = bf16r(alo.y);
        av.u[2]  = bf16r(alo.z); av.u[3]  = bf16r(alo.w);
        av.u[4]  = bf16r(ahi.x); av.u[5]  = bf16r(ahi.y);
        av.u[6]  = bf16r(ahi.z); av.u[7]  = bf16r(ahi.w);
        bv1.u[0] = bf16r(b1l.x); bv1.u[1] = bf16r(b1l.y);
        bv1.u[2] = bf16r(b1l.z); bv1.u[3] = bf16r(b1l.w);
        bv1.u[4] = bf16r(b1h.x); bv1.u[5] = bf16r(b1h.y);
        bv1.u[6] = bf16r(b1h.z); bv1.u[7] = bf16r(b1h.w);
        bv2.u[0] = bf16r(b2l.x); bv2.u[1] = bf16r(b2l.y);
        bv2.u[2] = bf16r(b2l.z); bv2.u[3] = bf16r(b2l.w);
        bv2.u[4] = bf16r(b2h.x); bv2.u[5] = bf16r(b2h.y);
        bv2.u[6] = bf16r(b2h.z); bv2.u[7] = bf16r(b2h.w);

        acc0 = __builtin_amdgcn_mfma_f32_32x32x16_bf16(av.v, bv1.v, acc0, 0, 0, 0);
        acc1 = __builtin_amdgcn_mfma_f32_32x32x16_bf16(av.v, bv2.v, acc1, 0, 0, 0);
    }

    // C/D layout (verified): col = lane&31, row = (reg&3) + 8*(reg>>2) + 4*(lane>>5)
    float* qpk = qp + ((size_t)ks * B + b) * N * C;
    #pragma unroll
    for (int reg = 0; reg < 16; reg++) {
        const int row = (reg & 3) + 8 * (reg >> 2) + 4 * kh;
        if (row < N) {
            if (c1 < C) qpk[row * C + c1] = acc0[reg];
            if (c2 < C) qpk[row * C + c2] = acc1[reg];
        }
    }
}

// ---------------- K1b: reduce KSPLIT partials ----------------
__global__ __launch_bounds__(256) void k1b_reduce(
    const float* __restrict__ qp, float* __restrict__ q)
{
    const int i = blockIdx.x * 256 + threadIdx.x;
    constexpr int S = B * N * C;
    if (i < S) {
        float s = 0.f;
        #pragma unroll
        for (int p = 0; p < KSPLIT; p++) s += qp[(size_t)p * S + i];
        q[i] = s;
    }
}

// ---------------- K2: BN stats per joint over (B, C) ----------------
__global__ __launch_bounds__(256) void k2_bnstats(
    const float* __restrict__ q,       // [B][N][C]
    const float* __restrict__ gamma,   // [N]
    const float* __restrict__ beta,    // [N]
    float* __restrict__ stats)         // [N][2] -> scale, shift
{
    const int n = blockIdx.x;
    const int tid = threadIdx.x;
    float s = 0.f, s2 = 0.f;
    if (tid < C) {
        for (int b = 0; b < B; b++) {
            const float v = q[((size_t)b * N + n) * C + tid];
            s += v; s2 += v * v;
        }
    }
    for (int off = 32; off; off >>= 1) {
        s  += __shfl_down(s,  off);
        s2 += __shfl_down(s2, off);
    }
    __shared__ float rs[4], rs2[4];
    const int wave = tid >> 6, lane = tid & 63;
    if (lane == 0) { rs[wave] = s; rs2[wave] = s2; }
    __syncthreads();
    if (tid == 0) {
        const float S  = rs[0] + rs[1] + rs[2] + rs[3];
        const float S2 = rs2[0] + rs2[1] + rs2[2] + rs2[3];
        const float cnt = (float)(B * C);
        const float mean = S / cnt;
        const float var  = S2 / cnt - mean * mean;
        const float scale = gamma[n] * rsqrtf(var + 1e-5f);
        stats[2 * n]     = scale;
        stats[2 * n + 1] = beta[n] - mean * scale;
    }
}

// ---------------- K3: BN-apply + LeakyReLU + GAT + Cheb ----------------
__global__ __launch_bounds__(256) void k3_tail(
    const float* __restrict__ q,        // [B][N][C]
    const float* __restrict__ stats,    // [N][2]
    const float* __restrict__ gatw,     // [C][HO]
    const float* __restrict__ attsrc,   // [4][32]
    const float* __restrict__ attdst,   // [4][32]
    const float* __restrict__ gatbias,  // [HO]
    const float* __restrict__ chebw,    // [2][HO][3]
    const float* __restrict__ chebbias, // [3]
    const float* __restrict__ adj,      // [N][N]
    const int* __restrict__ esrc,
    const int* __restrict__ edst,
    float* __restrict__ out)            // [B][N][3]
{
    __shared__ float ql[N][C + 1];
    __shared__ float Wl[48][HO];
    __shared__ float hl[N][HO];
    __shared__ float xl[N][HO];
    __shared__ float asrcl[N][4], adstl[N][4];
    __shared__ float el[E][4], alphal[E][4];
    __shared__ float mx[N][4], den[N][4];
    __shared__ float zl[N][3], t0l[N][3], dsl[N];
    __shared__ int esl[E], edl[E];

    const int b = blockIdx.x;
    const int tid = threadIdx.x;

    for (int v = tid; v < N * C; v += 256) {
        const int n = v / C, c = v % C;
        float x = q[((size_t)b * N + n) * C + c];
        x = x * stats[2 * n] + stats[2 * n + 1];
        ql[n][c] = (x >= 0.f) ? x : 0.1f * x;
    }
    if (tid < E) { esl[tid] = esrc[tid]; edl[tid] = edst[tid]; }
    for (int v = tid; v < N * HO; v += 256) hl[v >> 7][v & 127] = 0.f;
    __syncthreads();

    for (int k0 = 0; k0 < C; k0 += 48) {
        const int kc = (C - k0) < 48 ? (C - k0) : 48;
        for (int v = tid; v < kc * HO; v += 256) {
            const int kk = v >> 7, o = v & 127;
            Wl[kk][o] = gatw[(size_t)(k0 + kk) * HO + o];
        }
        __syncthreads();
        for (int idx = tid; idx < N * HO; idx += 256) {
            const int n = idx >> 7, o = idx & 127;
            float s = hl[n][o];
            for (int kk = 0; kk < kc; kk++)
                s += ql[n][k0 + kk] * Wl[kk][o];
            hl[n][o] = s;
        }
        __syncthreads();
    }

    if (tid < N * 4) {
        const int n = tid >> 2, h = tid & 3;
        float ss = 0.f, sd = 0.f;
        for (int fo = 0; fo < 32; fo++) {
            const float hv = hl[n][h * 32 + fo];
            ss += hv * attsrc[h * 32 + fo];
            sd += hv * attdst[h * 32 + fo];
        }
        asrcl[n][h] = ss; adstl[n][h] = sd;
    }
    __syncthreads();
    if (tid < E * 4) {
        const int e = tid >> 2, h = tid & 3;
        const float v = asrcl[esl[e]][h] + adstl[edl[e]][h];
        el[e][h] = (v >= 0.f) ? v : 0.2f * v;
    }
    __syncthreads();
    if (tid < N * 4) {
        const int n = tid >> 2, h = tid & 3;
        float m = -1e30f;
        for (int e = 0; e < E; e++)
            if (edl[e] == n) m = fmaxf(m, el[e][h]);
        mx[n][h] = m;
    }
    __syncthreads();
    if (tid < E * 4) {
        const int e = tid >> 2, h = tid & 3;
        el[e][h] = __expf(el[e][h] - mx[edl[e]][h]);
    }
    __syncthreads();
    if (tid < N * 4) {
        const int n = tid >> 2, h = tid & 3;
        float s = 0.f;
        for (int e = 0; e < E; e++)
            if (edl[e] == n) s += el[e][h];
        den[n][h] = s;
    }
    __syncthreads();
    if (tid < E * 4) {
        const int e = tid >> 2, h = tid & 3;
        alphal[e][h] = el[e][h] / den[edl[e]][h];
    }
    __syncthreads();

    for (int idx = tid; idx < N * HO; idx += 256) {
        const int n = idx >> 7, o = idx & 127, h = o >> 5;
        float s = 0.f;
        for (int e = 0; e < E; e++)
            if (edl[e] == n) s += alphal[e][h] * hl[esl[e]][o];
        xl[n][o] = s + gatbias[o];
    }
    if (tid < N) {
        float s = 0.f;
        for (int j = 0; j < N; j++) s += adj[tid * N + j];
        dsl[tid] = rsqrtf(s);
    }
    __syncthreads();

    if (tid < N * 3) {
        const int n = tid / 3, o = tid % 3;
        float s0 = 0.f, sz = 0.f;
        for (int c2 = 0; c2 < HO; c2++) {
            const float xv = xl[n][c2];
            s0 += xv * chebw[(size_t)c2 * 3 + o];
            sz += xv * chebw[(size_t)(HO + c2) * 3 + o];
        }
        t0l[n][o] = s0; zl[n][o] = sz;
    }
    __syncthreads();
    if (tid < N * 3) {
        const int m = tid / 3, o = tid % 3;
        float s = t0l[m][o] + zl[m][o];
        for (int n2 = 0; n2 < N; n2++)
            s -= dsl[m] * adj[m * N + n2] * dsl[n2] * zl[n2][o];
        out[(size_t)b * N * 3 + tid] = s + chebbias[o];
    }
}

extern "C" void kernel_launch(void* const* d_in, const int* in_sizes, int n_in,
                              void* d_out, int out_size, void* d_ws, size_t ws_size,
                              hipStream_t stream) {
    const float* feature  = (const float*)d_in[0];
    const float* target   = (const float*)d_in[1];
    const float* gamma    = (const float*)d_in[2];
    const float* beta     = (const float*)d_in[3];
    const float* gatw     = (const float*)d_in[4];
    const float* attsrc   = (const float*)d_in[5];
    const float* attdst   = (const float*)d_in[6];
    const float* gatbias  = (const float*)d_in[7];
    const float* chebw    = (const float*)d_in[8];
    const float* chebbias = (const float*)d_in[9];
    const float* adj      = (const float*)d_in[10];
    const int*   esrc     = (const int*)d_in[11];
    const int*   edst     = (const int*)d_in[12];

    constexpr int QS = B * N * C;
    float* qp    = (float*)d_ws;                    // [KSPLIT][B][N][C]
    float* q     = qp + (size_t)KSPLIT * QS;        // [B][N][C]
    float* stats = q + QS;                          // [N][2]
    float* out   = (float*)d_out;

    hipLaunchKernelGGL(k1_qgemm, dim3(KSPLIT, B), dim3(256), 0, stream,
                       feature, target, qp);
    hipLaunchKernelGGL(k1b_reduce, dim3((QS + 255) / 256), dim3(256), 0, stream, qp, q);
    hipLaunchKernelGGL(k2_bnstats, dim3(N), dim3(256), 0, stream, q, gamma, beta, stats);
    hipLaunchKernelGGL(k3_tail, dim3(B), dim3(256), 0, stream,
                       q, stats, gatw, attsrc, attdst, gatbias, chebw, chebbias,
                       adj, esrc, edst, out);
}